// Round 1
// baseline (778.742 us; speedup 1.0000x reference)
//
#include <hip/hip_runtime.h>
#include <hip/hip_bf16.h>

typedef __bf16 bf16x8 __attribute__((ext_vector_type(8)));
typedef float f32x4 __attribute__((ext_vector_type(4)));
typedef unsigned short u16x4 __attribute__((ext_vector_type(4)));
typedef unsigned short u16x8 __attribute__((ext_vector_type(8)));

#define B_DIM 8
#define N_SEQ 2048
#define D_DIM 256
#define KVBLK 32
#define QBLK 64
// (1/sqrt(256)) * log2(e)
#define SC_LOG2 0.09016844005556021f

#if __has_builtin(__builtin_amdgcn_exp2f)
#define EXP2F(x) __builtin_amdgcn_exp2f(x)
#else
#define EXP2F(x) exp2f(x)
#endif

// One block: 4 waves, 64 q-rows (16 per wave), one direction, one batch.
// Flash attention over KV tiles of 32 rows. K read direct from global
// (L2-resident); V staged transposed in LDS as bf16.
__global__ __launch_bounds__(256, 2)
void mca_attn(const float* __restrict__ x1, const float* __restrict__ x2,
              float* __restrict__ out) {
  const int b   = blockIdx.y;
  const int dir = blockIdx.z;
  const float* Qg = (dir ? x2 : x1) + (size_t)b * N_SEQ * D_DIM;
  const float* Kg = (dir ? x1 : x2) + (size_t)b * N_SEQ * D_DIM;
  float* outg = out + (size_t)b * N_SEQ * D_DIM;

  const int tid = threadIdx.x;
  const int w  = tid >> 6;
  const int l  = tid & 63;
  const int lr = l & 15;   // A-row / B-col lane index
  const int lg = l >> 4;   // k-group

  // V^T tile: Vt[d][kv], bf16 bits. Row stride 40 ushorts (80B) keeps
  // b128 writes / b64 reads bank-balanced and 8/16B-aligned.
  __shared__ unsigned short Vt[D_DIM][KVBLK + 8];

  const int row0 = blockIdx.x * QBLK + w * 16;  // wave's first q row

  // ---- Q fragments (held all kernel): qf[kt][j] = Q[row0+lr][kt*32+lg*8+j]
  bf16x8 qf[8];
  {
    const float* qrow = Qg + (size_t)(row0 + lr) * D_DIM + lg * 8;
    #pragma unroll
    for (int kt = 0; kt < 8; ++kt) {
      float4 a  = *(const float4*)(qrow + kt * 32);
      float4 bq = *(const float4*)(qrow + kt * 32 + 4);
      bf16x8 q;
      q[0] = (__bf16)a.x;  q[1] = (__bf16)a.y;  q[2] = (__bf16)a.z;  q[3] = (__bf16)a.w;
      q[4] = (__bf16)bq.x; q[5] = (__bf16)bq.y; q[6] = (__bf16)bq.z; q[7] = (__bf16)bq.w;
      qf[kt] = q;
    }
  }

  f32x4 oacc[16];
  #pragma unroll
  for (int i = 0; i < 16; ++i) oacc[i] = (f32x4){0.f, 0.f, 0.f, 0.f};
  float m_run = -1e30f;
  float l_run = 0.0f;

  for (int kv0 = 0; kv0 < N_SEQ; kv0 += KVBLK) {
    // ---- stage V^T: thread tid owns column d = tid (32 strided loads) ----
    {
      const float* col = Kg + (size_t)kv0 * D_DIM + tid;
      #pragma unroll
      for (int blk = 0; blk < 4; ++blk) {
        u16x8 pk;
        #pragma unroll
        for (int j = 0; j < 8; ++j) {
          float v = col[(size_t)(blk * 8 + j) * D_DIM];
          __bf16 h = (__bf16)v;
          pk[j] = __builtin_bit_cast(unsigned short, h);
        }
        *(u16x8*)&Vt[tid][blk * 8] = pk;   // 16B store, bank-balanced
      }
    }
    __syncthreads();

    // ---- S^T tile: T = K_tile · Q^T  → lane holds S[q=lr][kv=mt*16+4*lg+r]
    f32x4 tacc[2] = {(f32x4){0.f,0.f,0.f,0.f}, (f32x4){0.f,0.f,0.f,0.f}};
    #pragma unroll
    for (int kt = 0; kt < 8; ++kt) {
      #pragma unroll
      for (int mt = 0; mt < 2; ++mt) {
        const float* krow = Kg + (size_t)(kv0 + mt * 16 + lr) * D_DIM + kt * 32 + lg * 8;
        float4 a  = *(const float4*)(krow);
        float4 bk = *(const float4*)(krow + 4);
        bf16x8 kf;
        kf[0] = (__bf16)a.x;  kf[1] = (__bf16)a.y;  kf[2] = (__bf16)a.z;  kf[3] = (__bf16)a.w;
        kf[4] = (__bf16)bk.x; kf[5] = (__bf16)bk.y; kf[6] = (__bf16)bk.z; kf[7] = (__bf16)bk.w;
        tacc[mt] = __builtin_amdgcn_mfma_f32_16x16x32_bf16(kf, qf[kt], tacc[mt], 0, 0, 0);
      }
    }

    // ---- online softmax (per lane: row q = lr) ----
    float p[2][4];
    float tm = -1e30f;
    #pragma unroll
    for (int mt = 0; mt < 2; ++mt)
      #pragma unroll
      for (int r = 0; r < 4; ++r) {
        float s = tacc[mt][r] * SC_LOG2;
        p[mt][r] = s;
        tm = fmaxf(tm, s);
      }
    tm = fmaxf(tm, __shfl_xor(tm, 16));
    tm = fmaxf(tm, __shfl_xor(tm, 32));
    float m_new = fmaxf(m_run, tm);
    float fb = EXP2F(m_run - m_new);
    float rs = 0.0f;
    #pragma unroll
    for (int mt = 0; mt < 2; ++mt)
      #pragma unroll
      for (int r = 0; r < 4; ++r) {
        float e = EXP2F(p[mt][r] - m_new);
        p[mt][r] = e;
        rs += e;
      }
    rs += __shfl_xor(rs, 16);
    rs += __shfl_xor(rs, 32);
    l_run = l_run * fb + rs;
    m_run = m_new;

    // rescale O: O-row for reg r is q = 4*lg + r; fetch that row's factor
    float fq0 = __shfl(fb, lg * 4 + 0);
    float fq1 = __shfl(fb, lg * 4 + 1);
    float fq2 = __shfl(fb, lg * 4 + 2);
    float fq3 = __shfl(fb, lg * 4 + 3);
    #pragma unroll
    for (int dt = 0; dt < 16; ++dt) {
      f32x4 o = oacc[dt];
      o[0] *= fq0; o[1] *= fq1; o[2] *= fq2; o[3] *= fq3;
      oacc[dt] = o;
    }

    // ---- P fragment: pf[4*mt + r] = P[q=lr][kv = 16*mt + 4*lg + r] ----
    bf16x8 pf;
    #pragma unroll
    for (int mt = 0; mt < 2; ++mt)
      #pragma unroll
      for (int r = 0; r < 4; ++r)
        pf[mt * 4 + r] = (__bf16)p[mt][r];

    // ---- PV: V read with the SAME k-slot map as P ----
    #pragma unroll
    for (int dt = 0; dt < 16; ++dt) {
      u16x4 v0 = *(const u16x4*)&Vt[dt * 16 + lr][lg * 4];
      u16x4 v1 = *(const u16x4*)&Vt[dt * 16 + lr][16 + lg * 4];
      u16x8 vv = {v0[0], v0[1], v0[2], v0[3], v1[0], v1[1], v1[2], v1[3]};
      bf16x8 vf = __builtin_bit_cast(bf16x8, vv);
      oacc[dt] = __builtin_amdgcn_mfma_f32_16x16x32_bf16(pf, vf, oacc[dt], 0, 0, 0);
    }
    __syncthreads();
  }

  // ---- epilogue: normalize and accumulate into out ----
  float inv = 1.0f / l_run;               // per lane: row q = lr
  float iq0 = __shfl(inv, lg * 4 + 0);
  float iq1 = __shfl(inv, lg * 4 + 1);
  float iq2 = __shfl(inv, lg * 4 + 2);
  float iq3 = __shfl(inv, lg * 4 + 3);
  #pragma unroll
  for (int dt = 0; dt < 16; ++dt) {
    float* o0 = outg + (size_t)(row0 + lg * 4) * D_DIM + dt * 16 + lr;
    atomicAdd(o0 + 0 * D_DIM, oacc[dt][0] * iq0);
    atomicAdd(o0 + 1 * D_DIM, oacc[dt][1] * iq1);
    atomicAdd(o0 + 2 * D_DIM, oacc[dt][2] * iq2);
    atomicAdd(o0 + 3 * D_DIM, oacc[dt][3] * iq3);
  }
}

extern "C" void kernel_launch(void* const* d_in, const int* in_sizes, int n_in,
                              void* d_out, int out_size, void* d_ws, size_t ws_size,
                              hipStream_t stream) {
  const float* x1 = (const float*)d_in[0];
  const float* x2 = (const float*)d_in[1];
  float* out = (float*)d_out;

  // out is poisoned before every call; both directions atomically accumulate.
  hipMemsetAsync(out, 0, (size_t)out_size * sizeof(float), stream);

  dim3 grid(N_SEQ / QBLK, B_DIM, 2);
  dim3 block(256);
  mca_attn<<<grid, block, 0, stream>>>(x1, x2, out);
}

// Round 2
// 548.520 us; speedup vs baseline: 1.4197x; 1.4197x over previous
//
#include <hip/hip_runtime.h>
#include <hip/hip_bf16.h>

typedef __bf16 bf16x8 __attribute__((ext_vector_type(8)));
typedef float f32x4 __attribute__((ext_vector_type(4)));
typedef unsigned short u16x4 __attribute__((ext_vector_type(4)));
typedef unsigned short u16x8 __attribute__((ext_vector_type(8)));

#define B_DIM 8
#define N_SEQ 2048
#define D_DIM 256
#define KVBLK 32
#define QBLK 64
#define NB (B_DIM * N_SEQ * D_DIM)   // 4,194,304 elements per tensor
// (1/sqrt(256)) * log2(e)
#define SC_LOG2 0.09016844005556021f

#if __has_builtin(__builtin_amdgcn_exp2f)
#define EXP2F(x) __builtin_amdgcn_exp2f(x)
#else
#define EXP2F(x) exp2f(x)
#endif

// ---------------- conversion: x1,x2 f32 -> bf16 (packed [2][B][N][D]) -------
__global__ __launch_bounds__(256)
void cvt_bf16(const float* __restrict__ x1, const float* __restrict__ x2,
              unsigned short* __restrict__ dst) {
  size_t i = ((size_t)blockIdx.x * 256 + threadIdx.x) * 8;   // 8 elems/thread
  const float* src = (i < (size_t)NB) ? (x1 + i) : (x2 + (i - NB));
  float4 a = *(const float4*)src;
  float4 b = *(const float4*)(src + 4);
  u16x8 o;
  o[0] = __builtin_bit_cast(unsigned short, (__bf16)a.x);
  o[1] = __builtin_bit_cast(unsigned short, (__bf16)a.y);
  o[2] = __builtin_bit_cast(unsigned short, (__bf16)a.z);
  o[3] = __builtin_bit_cast(unsigned short, (__bf16)a.w);
  o[4] = __builtin_bit_cast(unsigned short, (__bf16)b.x);
  o[5] = __builtin_bit_cast(unsigned short, (__bf16)b.y);
  o[6] = __builtin_bit_cast(unsigned short, (__bf16)b.z);
  o[7] = __builtin_bit_cast(unsigned short, (__bf16)b.w);
  *(u16x8*)(dst + i) = o;
}

// ---------------- combine: out += ws1 ---------------------------------------
__global__ __launch_bounds__(256)
void combine_add(float* __restrict__ out, const float* __restrict__ o1) {
  size_t i = (size_t)blockIdx.x * 256 + threadIdx.x;
  float4 v = ((const float4*)out)[i];
  float4 w = ((const float4*)o1)[i];
  v.x += w.x; v.y += w.y; v.z += w.z; v.w += w.w;
  ((float4*)out)[i] = v;
}

// ---------------- main attention (bf16 inputs, double-buffered V^T) ---------
// One block: 4 waves, 64 q-rows (16/wave), one direction, one batch.
__global__ __launch_bounds__(256, 2)
void mca_attn_bf16(const unsigned short* __restrict__ xb,
                   float* __restrict__ out0, float* __restrict__ out1) {
  const int b   = blockIdx.y;
  const int dir = blockIdx.z;
  const unsigned short* Qb = xb + (size_t)(dir ? NB : 0) + (size_t)b * N_SEQ * D_DIM;
  const unsigned short* Kb = xb + (size_t)(dir ? 0 : NB) + (size_t)b * N_SEQ * D_DIM;
  float* outg = (dir ? out1 : out0) + (size_t)b * N_SEQ * D_DIM;

  const int tid = threadIdx.x;
  const int w  = tid >> 6;
  const int l  = tid & 63;
  const int lr = l & 15;   // A-row / B-col lane index
  const int lg = l >> 4;   // k-group

  // V^T tiles (double-buffered): Vt[buf][d][kv]; row stride 40 u16 (80B).
  __shared__ unsigned short Vt[2][D_DIM][KVBLK + 8];

  const int row0 = blockIdx.x * QBLK + w * 16;  // wave's first q row

  // ---- Q fragments: qf[kt][j] = Q[row0+lr][kt*32+lg*8+j] (bf16 direct) ----
  bf16x8 qf[8];
  {
    const unsigned short* qrow = Qb + (size_t)(row0 + lr) * D_DIM + lg * 8;
    #pragma unroll
    for (int kt = 0; kt < 8; ++kt)
      qf[kt] = *(const bf16x8*)(qrow + kt * 32);
  }

  f32x4 oacc[16];
  #pragma unroll
  for (int i = 0; i < 16; ++i) oacc[i] = (f32x4){0.f, 0.f, 0.f, 0.f};
  float m_run = -1e30f;
  float l_run = 0.0f;

  // staging registers (thread owns V^T column d = tid)
  u16x8 pk[4];
  const unsigned short* colbase = Kb + tid;

  // prologue: stage tile 0
  #pragma unroll
  for (int blk = 0; blk < 4; ++blk)
    #pragma unroll
    for (int j = 0; j < 8; ++j)
      pk[blk][j] = colbase[(size_t)(blk * 8 + j) * D_DIM];
  #pragma unroll
  for (int blk = 0; blk < 4; ++blk)
    *(u16x8*)&Vt[0][tid][blk * 8] = pk[blk];
  __syncthreads();

  int cur = 0;
  for (int t = 0; t < N_SEQ / KVBLK; ++t) {
    const int kv0 = t * KVBLK;

    // ---- issue next tile's staging loads EARLY (hide under compute) ----
    if (t + 1 < N_SEQ / KVBLK) {
      const unsigned short* col = colbase + (size_t)(kv0 + KVBLK) * D_DIM;
      #pragma unroll
      for (int blk = 0; blk < 4; ++blk)
        #pragma unroll
        for (int j = 0; j < 8; ++j)
          pk[blk][j] = col[(size_t)(blk * 8 + j) * D_DIM];
    }

    // ---- S^T tile: T = K_tile · Q^T  → lane holds S[q=lr][kv=mt*16+4*lg+r]
    f32x4 tacc[2] = {(f32x4){0.f,0.f,0.f,0.f}, (f32x4){0.f,0.f,0.f,0.f}};
    #pragma unroll
    for (int kt = 0; kt < 8; ++kt) {
      #pragma unroll
      for (int mt = 0; mt < 2; ++mt) {
        bf16x8 kf = *(const bf16x8*)(Kb + (size_t)(kv0 + mt * 16 + lr) * D_DIM
                                        + kt * 32 + lg * 8);
        tacc[mt] = __builtin_amdgcn_mfma_f32_16x16x32_bf16(kf, qf[kt], tacc[mt], 0, 0, 0);
      }
    }

    // ---- online softmax (per lane: row q = lr) ----
    float p[2][4];
    float tm = -1e30f;
    #pragma unroll
    for (int mt = 0; mt < 2; ++mt)
      #pragma unroll
      for (int r = 0; r < 4; ++r) {
        float s = tacc[mt][r] * SC_LOG2;
        p[mt][r] = s;
        tm = fmaxf(tm, s);
      }
    tm = fmaxf(tm, __shfl_xor(tm, 16));
    tm = fmaxf(tm, __shfl_xor(tm, 32));
    float m_new = fmaxf(m_run, tm);
    float fb = EXP2F(m_run - m_new);
    float rs = 0.0f;
    #pragma unroll
    for (int mt = 0; mt < 2; ++mt)
      #pragma unroll
      for (int r = 0; r < 4; ++r) {
        float e = EXP2F(p[mt][r] - m_new);
        p[mt][r] = e;
        rs += e;
      }
    rs += __shfl_xor(rs, 16);
    rs += __shfl_xor(rs, 32);
    l_run = l_run * fb + rs;
    m_run = m_new;

    // rescale O: O-row for reg r is q = 4*lg + r
    float fq0 = __shfl(fb, lg * 4 + 0);
    float fq1 = __shfl(fb, lg * 4 + 1);
    float fq2 = __shfl(fb, lg * 4 + 2);
    float fq3 = __shfl(fb, lg * 4 + 3);
    #pragma unroll
    for (int dt = 0; dt < 16; ++dt) {
      f32x4 o = oacc[dt];
      o[0] *= fq0; o[1] *= fq1; o[2] *= fq2; o[3] *= fq3;
      oacc[dt] = o;
    }

    // ---- P fragment: pf[4*mt + r] = P[q=lr][kv = 16*mt + 4*lg + r] ----
    bf16x8 pf;
    #pragma unroll
    for (int mt = 0; mt < 2; ++mt)
      #pragma unroll
      for (int r = 0; r < 4; ++r)
        pf[mt * 4 + r] = (__bf16)p[mt][r];

    // ---- PV: V read with the SAME k-slot map as P ----
    #pragma unroll
    for (int dt = 0; dt < 16; ++dt) {
      u16x4 v0 = *(const u16x4*)&Vt[cur][dt * 16 + lr][lg * 4];
      u16x4 v1 = *(const u16x4*)&Vt[cur][dt * 16 + lr][16 + lg * 4];
      u16x8 vv = {v0[0], v0[1], v0[2], v0[3], v1[0], v1[1], v1[2], v1[3]};
      bf16x8 vf = __builtin_bit_cast(bf16x8, vv);
      oacc[dt] = __builtin_amdgcn_mfma_f32_16x16x32_bf16(pf, vf, oacc[dt], 0, 0, 0);
    }

    // ---- write next tile into the other buffer; one barrier per tile ----
    if (t + 1 < N_SEQ / KVBLK) {
      #pragma unroll
      for (int blk = 0; blk < 4; ++blk)
        *(u16x8*)&Vt[cur ^ 1][tid][blk * 8] = pk[blk];
    }
    __syncthreads();
    cur ^= 1;
  }

  // ---- epilogue: normalize, plain stores (no atomics) ----
  float inv = 1.0f / l_run;               // per lane: row q = lr
  float iq0 = __shfl(inv, lg * 4 + 0);
  float iq1 = __shfl(inv, lg * 4 + 1);
  float iq2 = __shfl(inv, lg * 4 + 2);
  float iq3 = __shfl(inv, lg * 4 + 3);
  #pragma unroll
  for (int dt = 0; dt < 16; ++dt) {
    float* o0 = outg + (size_t)(row0 + lg * 4) * D_DIM + dt * 16 + lr;
    o0[0 * D_DIM] = oacc[dt][0] * iq0;
    o0[1 * D_DIM] = oacc[dt][1] * iq1;
    o0[2 * D_DIM] = oacc[dt][2] * iq2;
    o0[3 * D_DIM] = oacc[dt][3] * iq3;
  }
}

// ---------------- fallback (round-1 kernel, f32 + atomics) ------------------
__global__ __launch_bounds__(256, 2)
void mca_attn(const float* __restrict__ x1, const float* __restrict__ x2,
              float* __restrict__ out) {
  const int b   = blockIdx.y;
  const int dir = blockIdx.z;
  const float* Qg = (dir ? x2 : x1) + (size_t)b * N_SEQ * D_DIM;
  const float* Kg = (dir ? x1 : x2) + (size_t)b * N_SEQ * D_DIM;
  float* outg = out + (size_t)b * N_SEQ * D_DIM;

  const int tid = threadIdx.x;
  const int w  = tid >> 6;
  const int l  = tid & 63;
  const int lr = l & 15;
  const int lg = l >> 4;

  __shared__ unsigned short Vt[D_DIM][KVBLK + 8];
  const int row0 = blockIdx.x * QBLK + w * 16;

  bf16x8 qf[8];
  {
    const float* qrow = Qg + (size_t)(row0 + lr) * D_DIM + lg * 8;
    #pragma unroll
    for (int kt = 0; kt < 8; ++kt) {
      float4 a  = *(const float4*)(qrow + kt * 32);
      float4 bq = *(const float4*)(qrow + kt * 32 + 4);
      bf16x8 q;
      q[0] = (__bf16)a.x;  q[1] = (__bf16)a.y;  q[2] = (__bf16)a.z;  q[3] = (__bf16)a.w;
      q[4] = (__bf16)bq.x; q[5] = (__bf16)bq.y; q[6] = (__bf16)bq.z; q[7] = (__bf16)bq.w;
      qf[kt] = q;
    }
  }

  f32x4 oacc[16];
  #pragma unroll
  for (int i = 0; i < 16; ++i) oacc[i] = (f32x4){0.f, 0.f, 0.f, 0.f};
  float m_run = -1e30f, l_run = 0.0f;

  for (int kv0 = 0; kv0 < N_SEQ; kv0 += KVBLK) {
    {
      const float* col = Kg + (size_t)kv0 * D_DIM + tid;
      #pragma unroll
      for (int blk = 0; blk < 4; ++blk) {
        u16x8 pkk;
        #pragma unroll
        for (int j = 0; j < 8; ++j) {
          __bf16 h = (__bf16)col[(size_t)(blk * 8 + j) * D_DIM];
          pkk[j] = __builtin_bit_cast(unsigned short, h);
        }
        *(u16x8*)&Vt[tid][blk * 8] = pkk;
      }
    }
    __syncthreads();

    f32x4 tacc[2] = {(f32x4){0.f,0.f,0.f,0.f}, (f32x4){0.f,0.f,0.f,0.f}};
    #pragma unroll
    for (int kt = 0; kt < 8; ++kt) {
      #pragma unroll
      for (int mt = 0; mt < 2; ++mt) {
        const float* krow = Kg + (size_t)(kv0 + mt * 16 + lr) * D_DIM + kt * 32 + lg * 8;
        float4 a  = *(const float4*)(krow);
        float4 bk = *(const float4*)(krow + 4);
        bf16x8 kf;
        kf[0] = (__bf16)a.x;  kf[1] = (__bf16)a.y;  kf[2] = (__bf16)a.z;  kf[3] = (__bf16)a.w;
        kf[4] = (__bf16)bk.x; kf[5] = (__bf16)bk.y; kf[6] = (__bf16)bk.z; kf[7] = (__bf16)bk.w;
        tacc[mt] = __builtin_amdgcn_mfma_f32_16x16x32_bf16(kf, qf[kt], tacc[mt], 0, 0, 0);
      }
    }

    float p[2][4];
    float tm = -1e30f;
    #pragma unroll
    for (int mt = 0; mt < 2; ++mt)
      #pragma unroll
      for (int r = 0; r < 4; ++r) {
        float s = tacc[mt][r] * SC_LOG2;
        p[mt][r] = s;
        tm = fmaxf(tm, s);
      }
    tm = fmaxf(tm, __shfl_xor(tm, 16));
    tm = fmaxf(tm, __shfl_xor(tm, 32));
    float m_new = fmaxf(m_run, tm);
    float fb = EXP2F(m_run - m_new);
    float rs = 0.0f;
    #pragma unroll
    for (int mt = 0; mt < 2; ++mt)
      #pragma unroll
      for (int r = 0; r < 4; ++r) {
        float e = EXP2F(p[mt][r] - m_new);
        p[mt][r] = e;
        rs += e;
      }
    rs += __shfl_xor(rs, 16);
    rs += __shfl_xor(rs, 32);
    l_run = l_run * fb + rs;
    m_run = m_new;

    float fq0 = __shfl(fb, lg * 4 + 0);
    float fq1 = __shfl(fb, lg * 4 + 1);
    float fq2 = __shfl(fb, lg * 4 + 2);
    float fq3 = __shfl(fb, lg * 4 + 3);
    #pragma unroll
    for (int dt = 0; dt < 16; ++dt) {
      f32x4 o = oacc[dt];
      o[0] *= fq0; o[1] *= fq1; o[2] *= fq2; o[3] *= fq3;
      oacc[dt] = o;
    }

    bf16x8 pf;
    #pragma unroll
    for (int mt = 0; mt < 2; ++mt)
      #pragma unroll
      for (int r = 0; r < 4; ++r)
        pf[mt * 4 + r] = (__bf16)p[mt][r];

    #pragma unroll
    for (int dt = 0; dt < 16; ++dt) {
      u16x4 v0 = *(const u16x4*)&Vt[dt * 16 + lr][lg * 4];
      u16x4 v1 = *(const u16x4*)&Vt[dt * 16 + lr][16 + lg * 4];
      u16x8 vv = {v0[0], v0[1], v0[2], v0[3], v1[0], v1[1], v1[2], v1[3]};
      bf16x8 vf = __builtin_bit_cast(bf16x8, vv);
      oacc[dt] = __builtin_amdgcn_mfma_f32_16x16x32_bf16(pf, vf, oacc[dt], 0, 0, 0);
    }
    __syncthreads();
  }

  float inv = 1.0f / l_run;
  float iq0 = __shfl(inv, lg * 4 + 0);
  float iq1 = __shfl(inv, lg * 4 + 1);
  float iq2 = __shfl(inv, lg * 4 + 2);
  float iq3 = __shfl(inv, lg * 4 + 3);
  #pragma unroll
  for (int dt = 0; dt < 16; ++dt) {
    float* o0 = outg + (size_t)(row0 + lg * 4) * D_DIM + dt * 16 + lr;
    atomicAdd(o0 + 0 * D_DIM, oacc[dt][0] * iq0);
    atomicAdd(o0 + 1 * D_DIM, oacc[dt][1] * iq1);
    atomicAdd(o0 + 2 * D_DIM, oacc[dt][2] * iq2);
    atomicAdd(o0 + 3 * D_DIM, oacc[dt][3] * iq3);
  }
}

extern "C" void kernel_launch(void* const* d_in, const int* in_sizes, int n_in,
                              void* d_out, int out_size, void* d_ws, size_t ws_size,
                              hipStream_t stream) {
  const float* x1 = (const float*)d_in[0];
  const float* x2 = (const float*)d_in[1];
  float* out = (float*)d_out;

  const size_t bf16_bytes = (size_t)2 * NB * sizeof(unsigned short); // 32 MiB
  const size_t out1_bytes = (size_t)NB * sizeof(float);              // 16 MiB

  if (ws_size >= bf16_bytes + out1_bytes) {
    unsigned short* xb = (unsigned short*)d_ws;
    float* out1 = (float*)((char*)d_ws + bf16_bytes);

    cvt_bf16<<<(2 * NB) / (256 * 8), 256, 0, stream>>>(x1, x2, xb);
    mca_attn_bf16<<<dim3(N_SEQ / QBLK, B_DIM, 2), 256, 0, stream>>>(xb, out, out1);
    combine_add<<<(NB / 4) / 256, 256, 0, stream>>>(out, out1);
  } else {
    hipMemsetAsync(out, 0, (size_t)out_size * sizeof(float), stream);
    mca_attn<<<dim3(N_SEQ / QBLK, B_DIM, 2), 256, 0, stream>>>(x1, x2, out);
  }
}

// Round 5
// 355.950 us; speedup vs baseline: 2.1878x; 1.5410x over previous
//
#include <hip/hip_runtime.h>
#include <hip/hip_bf16.h>

typedef __bf16 bf16x8 __attribute__((ext_vector_type(8)));
typedef float f32x4 __attribute__((ext_vector_type(4)));
typedef unsigned short u16x4 __attribute__((ext_vector_type(4)));
typedef unsigned short u16x8 __attribute__((ext_vector_type(8)));

#define B_DIM 8
#define N_SEQ 2048
#define D_DIM 256
#define QBLK 64
#define NB (B_DIM * N_SEQ * D_DIM)   // 4,194,304 elements per tensor
// (1/sqrt(256)) * log2(e)
#define SC_LOG2 0.09016844005556021f

#if __has_builtin(__builtin_amdgcn_exp2f)
#define EXP2F(x) __builtin_amdgcn_exp2f(x)
#else
#define EXP2F(x) exp2f(x)
#endif

__device__ __forceinline__ unsigned short bfbits(float f) {
  return __builtin_bit_cast(unsigned short, (__bf16)f);
}

// ---------------- prep: f32 -> bf16 row-major (xb) + bf16 transposed (xT) ---
// xb[2][B][N][D]: slot0=x1, slot1=x2.   xT[2][B][D][N]: slot0=x2^T, slot1=x1^T
// (xT slot s holds the transpose of the K/V tensor for direction s).
__global__ __launch_bounds__(256)
void prep_cvt_tr(const float* __restrict__ x1, const float* __restrict__ x2,
                 unsigned short* __restrict__ xb, unsigned short* __restrict__ xT) {
  __shared__ unsigned short Lt[64 * 72];   // 64n x 64d tile, stride 72
  const int t   = threadIdx.x;
  const int n0  = blockIdx.x * 64;
  const int d0  = blockIdx.y * 64;
  const int src = blockIdx.z >> 3;
  const int b   = blockIdx.z & 7;
  const float* g = (src ? x2 : x1) + (size_t)b * N_SEQ * D_DIM;
  unsigned short* xbp = xb + (size_t)src * NB + (size_t)b * N_SEQ * D_DIM;
  unsigned short* xTp = xT + (size_t)(src ^ 1) * NB + (size_t)b * D_DIM * N_SEQ;

  #pragma unroll
  for (int r = 0; r < 4; ++r) {
    const int nl = r * 16 + (t >> 4);
    const int dl = (t & 15) * 4;
    float4 v = *(const float4*)(g + (size_t)(n0 + nl) * D_DIM + d0 + dl);
    u16x4 wv;
    wv[0] = bfbits(v.x); wv[1] = bfbits(v.y); wv[2] = bfbits(v.z); wv[3] = bfbits(v.w);
    *(u16x4*)(xbp + (size_t)(n0 + nl) * D_DIM + d0 + dl) = wv;
    *(u16x4*)&Lt[nl * 72 + dl] = wv;
  }
  __syncthreads();
  #pragma unroll
  for (int r = 0; r < 4; ++r) {
    const int dl = r * 16 + (t >> 4);
    const int nl = (t & 15) * 4;
    u16x4 ov;
    ov[0] = Lt[(nl + 0) * 72 + dl];
    ov[1] = Lt[(nl + 1) * 72 + dl];
    ov[2] = Lt[(nl + 2) * 72 + dl];
    ov[3] = Lt[(nl + 3) * 72 + dl];
    *(u16x4*)(xTp + (size_t)(d0 + dl) * N_SEQ + n0 + nl) = ov;
  }
}

// ---------------- combine: out += ws1 ---------------------------------------
__global__ __launch_bounds__(256)
void combine_add(float* __restrict__ out, const float* __restrict__ o1) {
  size_t i = (size_t)blockIdx.x * 256 + threadIdx.x;
  float4 v = ((const float4*)out)[i];
  float4 w = ((const float4*)o1)[i];
  v.x += w.x; v.y += w.y; v.z += w.z; v.w += w.w;
  ((float4*)out)[i] = v;
}

// ---------------- async V^T staging: 8x global_load_lds(16B) per wave -------
// LDS layout (per tile, 256 d x 64 kv bf16 = 32KB):
//   element(d, kv) = d*64 + (kv ^ (8*(d&7)))      [16B-granule XOR swizzle]
// Destination is linear (gload_lds requirement); the swizzle is pre-applied
// to the per-lane GLOBAL source granule (both-sides rule).
__device__ __forceinline__ void stageV(const unsigned short* __restrict__ VTg,
                                       unsigned short* ldsbuf, int kv0,
                                       int w, int l) {
  const int lsub = l >> 3;                 // 0..7: d sub-row within instruction
  const int g    = (l & 7) ^ lsub;         // swizzled source granule (16B)
  #pragma unroll
  for (int k = 0; k < 8; ++k) {
    const int i = w * 8 + k;               // instruction id 0..31 over the block
    const int d = i * 8 + lsub;            // d row 0..255
    const unsigned short* src = VTg + (size_t)d * N_SEQ + kv0 + g * 8;
    unsigned short* dst = ldsbuf + i * 512;  // wave-uniform; HW adds lane*16B
    __builtin_amdgcn_global_load_lds(
        (const __attribute__((address_space(1))) unsigned int*)src,
        (__attribute__((address_space(3))) unsigned int*)dst, 16, 0, 0);
  }
}

// ---------------- main attention v3 -----------------------------------------
// 4 waves, 64 q rows (16/wave), KVBLK=64, double-buffered async V^T staging,
// raw barriers with counted vmcnt, K fragments direct from global (L1/L2).
__global__ __launch_bounds__(256, 2)
void mca_attn_v3(const unsigned short* __restrict__ xb,
                 const unsigned short* __restrict__ xT,
                 float* __restrict__ out0, float* __restrict__ out1) {
  const int b   = blockIdx.y;
  const int dir = blockIdx.z;
  const unsigned short* Qb  = xb + (size_t)dir * NB + (size_t)b * N_SEQ * D_DIM;
  const unsigned short* Kb  = xb + (size_t)(dir ^ 1) * NB + (size_t)b * N_SEQ * D_DIM;
  const unsigned short* VTg = xT + (size_t)dir * NB + (size_t)b * D_DIM * N_SEQ;
  float* outg = (dir ? out1 : out0) + (size_t)b * N_SEQ * D_DIM;

  const int tid = threadIdx.x;
  const int w  = tid >> 6;
  const int l  = tid & 63;
  const int lr = l & 15;   // A-row / B-col lane index
  const int lg = l >> 4;   // k-group

  __shared__ unsigned short Vt[2][D_DIM * 64];   // 2 x 32KB

  const int row0 = blockIdx.x * QBLK + w * 16;

  // Q fragments: qf[kt][j] = Q[row0+lr][kt*32+lg*8+j]
  bf16x8 qf[8];
  {
    const unsigned short* qrow = Qb + (size_t)(row0 + lr) * D_DIM + lg * 8;
    #pragma unroll
    for (int kt = 0; kt < 8; ++kt)
      qf[kt] = *(const bf16x8*)(qrow + kt * 32);
  }

  f32x4 oacc[16];
  #pragma unroll
  for (int i = 0; i < 16; ++i) oacc[i] = (f32x4){0.f, 0.f, 0.f, 0.f};
  float m_run = -1e30f;
  float l_run = 0.0f;

  // prologue: stage tile 0 into buf 0
  stageV(VTg, &Vt[0][0], 0, w, l);
  asm volatile("s_waitcnt vmcnt(0)" ::: "memory");
  __builtin_amdgcn_s_barrier();

  const int sw = 8 * (lr & 7);   // LDS read swizzle (element units)

  for (int t = 0; t < N_SEQ / 64; ++t) {
    const int kv0 = t * 64;
    const int cur = t & 1;

    // ---- QK: tacc[mt], kv = 16*mt + 4*lg + r (r = reg), q col = lr --------
    f32x4 tacc[4];
    #pragma unroll
    for (int mt = 0; mt < 4; ++mt) tacc[mt] = (f32x4){0.f, 0.f, 0.f, 0.f};
    __builtin_amdgcn_s_setprio(1);
    #pragma unroll
    for (int kt = 0; kt < 8; ++kt) {
      #pragma unroll
      for (int mt = 0; mt < 4; ++mt) {
        bf16x8 kf = *(const bf16x8*)(Kb + (size_t)(kv0 + mt * 16 + lr) * D_DIM
                                        + kt * 32 + lg * 8);
        tacc[mt] = __builtin_amdgcn_mfma_f32_16x16x32_bf16(kf, qf[kt], tacc[mt], 0, 0, 0);
      }
    }
    __builtin_amdgcn_s_setprio(0);

    // ---- issue next tile's staging (async, stays in flight past barriers) --
    if (t + 1 < N_SEQ / 64)
      stageV(VTg, &Vt[cur ^ 1][0], kv0 + 64, w, l);

    // ---- online softmax over 64 kv (per lane: q row = lr) ------------------
    float p[4][4];
    float tm = -1e30f;
    #pragma unroll
    for (int mt = 0; mt < 4; ++mt)
      #pragma unroll
      for (int r = 0; r < 4; ++r) {
        float s = tacc[mt][r] * SC_LOG2;
        p[mt][r] = s;
        tm = fmaxf(tm, s);
      }
    tm = fmaxf(tm, __shfl_xor(tm, 16));
    tm = fmaxf(tm, __shfl_xor(tm, 32));
    float m_new = fmaxf(m_run, tm);
    float fb = EXP2F(m_run - m_new);
    float rs = 0.0f;
    #pragma unroll
    for (int mt = 0; mt < 4; ++mt)
      #pragma unroll
      for (int r = 0; r < 4; ++r) {
        float e = EXP2F(p[mt][r] - m_new);
        p[mt][r] = e;
        rs += e;
      }
    rs += __shfl_xor(rs, 16);
    rs += __shfl_xor(rs, 32);
    l_run = l_run * fb + rs;
    m_run = m_new;

    // rescale O: O-row for reg r is q = 4*lg + r
    float fq0 = __shfl(fb, lg * 4 + 0);
    float fq1 = __shfl(fb, lg * 4 + 1);
    float fq2 = __shfl(fb, lg * 4 + 2);
    float fq3 = __shfl(fb, lg * 4 + 3);
    #pragma unroll
    for (int dt = 0; dt < 16; ++dt) {
      f32x4 o = oacc[dt];
      o[0] *= fq0; o[1] *= fq1; o[2] *= fq2; o[3] *= fq3;
      oacc[dt] = o;
    }

    // P fragments: pf_h[j] = P[q=lr][kv = 32h + 16*(j>=4) + 4*lg + (j&3)]
    bf16x8 pf0, pf1;
    #pragma unroll
    for (int r = 0; r < 4; ++r) {
      pf0[r]     = (__bf16)p[0][r];
      pf0[r + 4] = (__bf16)p[1][r];
      pf1[r]     = (__bf16)p[2][r];
      pf1[r + 4] = (__bf16)p[3][r];
    }

    // barrier 1: tile t's staging complete everywhere.
    // vmcnt(8) = "all but the 8 newest VMEM ops done" -> tile-t loads (older
    // than this iteration's 8 stage ops + all QK loads) are retired.
    asm volatile("s_waitcnt vmcnt(8)" ::: "memory");
    __builtin_amdgcn_s_barrier();

    // ---- PV: V fragments from swizzled LDS; same k-slot map as P ----------
    __builtin_amdgcn_s_setprio(1);
    #pragma unroll
    for (int dt = 0; dt < 16; ++dt) {
      const int base = (dt * 16 + lr) * 64;
      u16x4 v00 = *(const u16x4*)&Vt[cur][base + ((     4 * lg) ^ sw)];
      u16x4 v01 = *(const u16x4*)&Vt[cur][base + ((16 + 4 * lg) ^ sw)];
      u16x4 v10 = *(const u16x4*)&Vt[cur][base + ((32 + 4 * lg) ^ sw)];
      u16x4 v11 = *(const u16x4*)&Vt[cur][base + ((48 + 4 * lg) ^ sw)];
      u16x8 c0 = {v00[0], v00[1], v00[2], v00[3], v01[0], v01[1], v01[2], v01[3]};
      u16x8 c1 = {v10[0], v10[1], v10[2], v10[3], v11[0], v11[1], v11[2], v11[3]};
      bf16x8 vf0 = __builtin_bit_cast(bf16x8, c0);
      bf16x8 vf1 = __builtin_bit_cast(bf16x8, c1);
      oacc[dt] = __builtin_amdgcn_mfma_f32_16x16x32_bf16(pf0, vf0, oacc[dt], 0, 0, 0);
      oacc[dt] = __builtin_amdgcn_mfma_f32_16x16x32_bf16(pf1, vf1, oacc[dt], 0, 0, 0);
    }
    __builtin_amdgcn_s_setprio(0);

    // barrier 2: everyone done reading Vt[cur]; safe to overwrite next iter.
    asm volatile("" ::: "memory");
    __builtin_amdgcn_s_barrier();
  }

  // ---- epilogue: normalize, plain stores ----
  float inv = 1.0f / l_run;
  float iq0 = __shfl(inv, lg * 4 + 0);
  float iq1 = __shfl(inv, lg * 4 + 1);
  float iq2 = __shfl(inv, lg * 4 + 2);
  float iq3 = __shfl(inv, lg * 4 + 3);
  #pragma unroll
  for (int dt = 0; dt < 16; ++dt) {
    float* o0 = outg + (size_t)(row0 + lg * 4) * D_DIM + dt * 16 + lr;
    o0[0 * D_DIM] = oacc[dt][0] * iq0;
    o0[1 * D_DIM] = oacc[dt][1] * iq1;
    o0[2 * D_DIM] = oacc[dt][2] * iq2;
    o0[3 * D_DIM] = oacc[dt][3] * iq3;
  }
}

// ---------------- fallback path (round-2, needs 48MB ws) --------------------
__global__ __launch_bounds__(256)
void cvt_bf16(const float* __restrict__ x1, const float* __restrict__ x2,
              unsigned short* __restrict__ dst) {
  size_t i = ((size_t)blockIdx.x * 256 + threadIdx.x) * 8;
  const float* src = (i < (size_t)NB) ? (x1 + i) : (x2 + (i - NB));
  float4 a = *(const float4*)src;
  float4 b = *(const float4*)(src + 4);
  u16x8 o;
  o[0] = bfbits(a.x); o[1] = bfbits(a.y); o[2] = bfbits(a.z); o[3] = bfbits(a.w);
  o[4] = bfbits(b.x); o[5] = bfbits(b.y); o[6] = bfbits(b.z); o[7] = bfbits(b.w);
  *(u16x8*)(dst + i) = o;
}

__global__ __launch_bounds__(256, 2)
void mca_attn_bf16(const unsigned short* __restrict__ xb,
                   float* __restrict__ out0, float* __restrict__ out1) {
  const int b   = blockIdx.y;
  const int dir = blockIdx.z;
  const unsigned short* Qb = xb + (size_t)(dir ? NB : 0) + (size_t)b * N_SEQ * D_DIM;
  const unsigned short* Kb = xb + (size_t)(dir ? 0 : NB) + (size_t)b * N_SEQ * D_DIM;
  float* outg = (dir ? out1 : out0) + (size_t)b * N_SEQ * D_DIM;

  const int tid = threadIdx.x;
  const int w  = tid >> 6;
  const int l  = tid & 63;
  const int lr = l & 15;
  const int lg = l >> 4;

  __shared__ unsigned short Vt[2][D_DIM][32 + 8];
  const int row0 = blockIdx.x * QBLK + w * 16;

  bf16x8 qf[8];
  {
    const unsigned short* qrow = Qb + (size_t)(row0 + lr) * D_DIM + lg * 8;
    #pragma unroll
    for (int kt = 0; kt < 8; ++kt)
      qf[kt] = *(const bf16x8*)(qrow + kt * 32);
  }

  f32x4 oacc[16];
  #pragma unroll
  for (int i = 0; i < 16; ++i) oacc[i] = (f32x4){0.f, 0.f, 0.f, 0.f};
  float m_run = -1e30f, l_run = 0.0f;

  u16x8 pk[4];
  const unsigned short* colbase = Kb + tid;

  #pragma unroll
  for (int blk = 0; blk < 4; ++blk)
    #pragma unroll
    for (int j = 0; j < 8; ++j)
      pk[blk][j] = colbase[(size_t)(blk * 8 + j) * D_DIM];
  #pragma unroll
  for (int blk = 0; blk < 4; ++blk)
    *(u16x8*)&Vt[0][tid][blk * 8] = pk[blk];
  __syncthreads();

  int cur = 0;
  for (int t = 0; t < N_SEQ / 32; ++t) {
    const int kv0 = t * 32;
    if (t + 1 < N_SEQ / 32) {
      const unsigned short* col = colbase + (size_t)(kv0 + 32) * D_DIM;
      #pragma unroll
      for (int blk = 0; blk < 4; ++blk)
        #pragma unroll
        for (int j = 0; j < 8; ++j)
          pk[blk][j] = col[(size_t)(blk * 8 + j) * D_DIM];
    }

    f32x4 tacc[2] = {(f32x4){0.f,0.f,0.f,0.f}, (f32x4){0.f,0.f,0.f,0.f}};
    #pragma unroll
    for (int kt = 0; kt < 8; ++kt) {
      #pragma unroll
      for (int mt = 0; mt < 2; ++mt) {
        bf16x8 kf = *(const bf16x8*)(Kb + (size_t)(kv0 + mt * 16 + lr) * D_DIM
                                        + kt * 32 + lg * 8);
        tacc[mt] = __builtin_amdgcn_mfma_f32_16x16x32_bf16(kf, qf[kt], tacc[mt], 0, 0, 0);
      }
    }

    float p[2][4];
    float tm = -1e30f;
    #pragma unroll
    for (int mt = 0; mt < 2; ++mt)
      #pragma unroll
      for (int r = 0; r < 4; ++r) {
        float s = tacc[mt][r] * SC_LOG2;
        p[mt][r] = s;
        tm = fmaxf(tm, s);
      }
    tm = fmaxf(tm, __shfl_xor(tm, 16));
    tm = fmaxf(tm, __shfl_xor(tm, 32));
    float m_new = fmaxf(m_run, tm);
    float fb = EXP2F(m_run - m_new);
    float rs = 0.0f;
    #pragma unroll
    for (int mt = 0; mt < 2; ++mt)
      #pragma unroll
      for (int r = 0; r < 4; ++r) {
        float e = EXP2F(p[mt][r] - m_new);
        p[mt][r] = e;
        rs += e;
      }
    rs += __shfl_xor(rs, 16);
    rs += __shfl_xor(rs, 32);
    l_run = l_run * fb + rs;
    m_run = m_new;

    float fq0 = __shfl(fb, lg * 4 + 0);
    float fq1 = __shfl(fb, lg * 4 + 1);
    float fq2 = __shfl(fb, lg * 4 + 2);
    float fq3 = __shfl(fb, lg * 4 + 3);
    #pragma unroll
    for (int dt = 0; dt < 16; ++dt) {
      f32x4 o = oacc[dt];
      o[0] *= fq0; o[1] *= fq1; o[2] *= fq2; o[3] *= fq3;
      oacc[dt] = o;
    }

    bf16x8 pf;
    #pragma unroll
    for (int mt = 0; mt < 2; ++mt)
      #pragma unroll
      for (int r = 0; r < 4; ++r)
        pf[mt * 4 + r] = (__bf16)p[mt][r];

    #pragma unroll
    for (int dt = 0; dt < 16; ++dt) {
      u16x4 v0 = *(const u16x4*)&Vt[cur][dt * 16 + lr][lg * 4];
      u16x4 v1 = *(const u16x4*)&Vt[cur][dt * 16 + lr][16 + lg * 4];
      u16x8 vv = {v0[0], v0[1], v0[2], v0[3], v1[0], v1[1], v1[2], v1[3]};
      bf16x8 vf = __builtin_bit_cast(bf16x8, vv);
      oacc[dt] = __builtin_amdgcn_mfma_f32_16x16x32_bf16(pf, vf, oacc[dt], 0, 0, 0);
    }

    if (t + 1 < N_SEQ / 32) {
      #pragma unroll
      for (int blk = 0; blk < 4; ++blk)
        *(u16x8*)&Vt[cur ^ 1][tid][blk * 8] = pk[blk];
    }
    __syncthreads();
    cur ^= 1;
  }

  float inv = 1.0f / l_run;
  float iq0 = __shfl(inv, lg * 4 + 0);
  float iq1 = __shfl(inv, lg * 4 + 1);
  float iq2 = __shfl(inv, lg * 4 + 2);
  float iq3 = __shfl(inv, lg * 4 + 3);
  #pragma unroll
  for (int dt = 0; dt < 16; ++dt) {
    float* o0 = outg + (size_t)(row0 + lg * 4) * D_DIM + dt * 16 + lr;
    o0[0 * D_DIM] = oacc[dt][0] * iq0;
    o0[1 * D_DIM] = oacc[dt][1] * iq1;
    o0[2 * D_DIM] = oacc[dt][2] * iq2;
    o0[3 * D_DIM] = oacc[dt][3] * iq3;
  }
}

extern "C" void kernel_launch(void* const* d_in, const int* in_sizes, int n_in,
                              void* d_out, int out_size, void* d_ws, size_t ws_size,
                              hipStream_t stream) {
  const float* x1 = (const float*)d_in[0];
  const float* x2 = (const float*)d_in[1];
  float* out = (float*)d_out;

  const size_t xb_b  = (size_t)2 * NB * sizeof(unsigned short); // 16 MiB
  const size_t xT_b  = (size_t)2 * NB * sizeof(unsigned short); // 16 MiB
  const size_t o1_b  = (size_t)NB * sizeof(float);              // 16 MiB

  if (ws_size >= xb_b + xT_b + o1_b) {
    unsigned short* xb = (unsigned short*)d_ws;
    unsigned short* xT = (unsigned short*)((char*)d_ws + xb_b);
    float* out1 = (float*)((char*)d_ws + xb_b + xT_b);

    prep_cvt_tr<<<dim3(N_SEQ / 64, D_DIM / 64, 16), 256, 0, stream>>>(x1, x2, xb, xT);
    mca_attn_v3<<<dim3(N_SEQ / QBLK, B_DIM, 2), 256, 0, stream>>>(xb, xT, out, out1);
    combine_add<<<(NB / 4) / 256, 256, 0, stream>>>(out, out1);
  } else {
    unsigned short* xb = (unsigned short*)d_ws;
    float* out1 = (float*)((char*)d_ws + xb_b);
    cvt_bf16<<<(2 * NB) / (256 * 8), 256, 0, stream>>>(x1, x2, xb);
    mca_attn_bf16<<<dim3(N_SEQ / QBLK, B_DIM, 2), 256, 0, stream>>>(xb, out, out1);
    combine_add<<<(NB / 4) / 256, 256, 0, stream>>>(out, out1);
  }
}